// Round 4
// baseline (18297.069 us; speedup 1.0000x reference)
//
#include <hip/hip_runtime.h>
#include <math.h>

#define D_DIM 512

typedef __attribute__((ext_vector_type(8))) short bf16x8;
typedef __attribute__((ext_vector_type(4))) float f32x4;

#define AS1 __attribute__((address_space(1)))
#define AS3 __attribute__((address_space(3)))

// async global->LDS, 16B per lane. LDS dest must be wave-uniform base + lane*16.
__device__ __forceinline__ void gload_lds16(const void* g, void* l) {
    __builtin_amdgcn_global_load_lds((AS1 const void*)g, (AS3 void*)l, 16, 0, 0);
}

// ---------- numpy pairwise-sum replica for sum(v*v) over 512 contiguous floats ----------
__device__ __forceinline__ float pw128_sq(const float* __restrict__ a) {
    float r[8];
    #pragma unroll
    for (int j = 0; j < 8; ++j) r[j] = __fmul_rn(a[j], a[j]);
    #pragma unroll
    for (int i = 8; i < 128; i += 8)
        #pragma unroll
        for (int j = 0; j < 8; ++j) r[j] = __fadd_rn(r[j], __fmul_rn(a[i + j], a[i + j]));
    float s01 = __fadd_rn(r[0], r[1]);
    float s23 = __fadd_rn(r[2], r[3]);
    float s45 = __fadd_rn(r[4], r[5]);
    float s67 = __fadd_rn(r[6], r[7]);
    return __fadd_rn(__fadd_rn(s01, s23), __fadd_rn(s45, s67));
}
__device__ __forceinline__ float rownorm512(const float* __restrict__ row) {
    float b0 = pw128_sq(row);
    float b1 = pw128_sq(row + 128);
    float b2 = pw128_sq(row + 256);
    float b3 = pw128_sq(row + 384);
    return __fadd_rn(__fadd_rn(b0, b1), __fadd_rn(b2, b3));
}

// ---------------- norms kernel (numpy-faithful f32) + optional zero of loss / cnt ----------------
__global__ void k_norms(const float* __restrict__ a, float* __restrict__ out, int nrows,
                        float* __restrict__ loss_ptr, unsigned* __restrict__ cnt) {
    int r = blockIdx.x * blockDim.x + threadIdx.x;
    if (r == 0 && loss_ptr) *loss_ptr = 0.0f;
    if (r >= nrows) return;
    if (cnt) cnt[r] = 0u;
    out[r] = rownorm512(a + (size_t)r * D_DIM);
}

// ---------------- f32 -> bf16 (RNE) convert, 8 elems/thread ----------------
__global__ void k_cvt_bf16(const float* __restrict__ src, unsigned short* __restrict__ dst,
                           size_t n8) {
    size_t i = blockIdx.x * (size_t)blockDim.x + threadIdx.x;
    if (i >= n8) return;
    const float4* s = (const float4*)(src + i * 8);
    float4 v0 = s[0], v1 = s[1];
    float vv[8] = {v0.x, v0.y, v0.z, v0.w, v1.x, v1.y, v1.z, v1.w};
    unsigned u[8];
    #pragma unroll
    for (int j = 0; j < 8; ++j) {
        unsigned b = __float_as_uint(vv[j]);
        b = b + 0x7FFFu + ((b >> 16) & 1u);
        u[j] = b >> 16;
    }
    uint4 w;
    w.x = u[0] | (u[1] << 16);
    w.y = u[2] | (u[3] << 16);
    w.z = u[4] | (u[5] << 16);
    w.w = u[6] | (u[7] << 16);
    *(uint4*)(dst + i * 8) = w;
}

// ---------------- MFMA filter sweep (v5: m97 geometry, multi-block/CU) ----------------
// grid (256 Mtiles, 4 code-quarters) = 1024 blocks -> 2-3 co-resident blocks/CU, which
// is the mechanism that hides the per-chunk barrier drain (inter-block overlap).
// Block: 256 threads = 4 waves as 2M x 2N (wave-tile 64x64, acc[4][4]).
// Block tile: 128 rows x 128 codes per nt step, BK=32, double-buffered LDS filled by
// global_load_lds (linear layout: at 64B row stride the wave's ds_read_b128s already
// cover all eight 16B bank slots uniformly -> no swizzle needed on either side).
// Loop structure identical to the verified R1 kernel: prefetch chunk g+1, compute
// chunk g, one __syncthreads per chunk. K-accumulation order per acc element is
// unchanged (ascending k, 16 x K=32 MFMA) -> bit-identical scores vs R0/R1.
#define THETA 4.0e-4f

__global__ __launch_bounds__(256, 2)
void k_score(const unsigned short* __restrict__ Abf, const unsigned short* __restrict__ Bbf,
             const float* __restrict__ s2, unsigned* __restrict__ cnt,
             unsigned* __restrict__ cand, int N, int K) {
    __shared__ unsigned short ldsA[2][128][32];   // 16 KiB
    __shared__ unsigned short ldsB[2][128][32];   // 16 KiB
    __shared__ int minb[128];

    const int tid  = threadIdx.x;
    const int lane = tid & 63;
    const int wid  = tid >> 6;            // 0..3
    const int wm   = (wid >> 1) * 64;     // 0,64
    const int wn   = (wid & 1) * 64;      // 0,64
    const int col  = lane & 15;
    const int q8   = lane >> 4;           // 0..3 (16B granule within the 64B row)
    const int m0   = blockIdx.x * 128;
    const int nquart = K >> 2;            // 2048
    const int nb0  = blockIdx.y * nquart;
    const int NT   = nquart >> 7;         // 16 code tiles of 128
    const int G    = NT * 16;             // total BK=32 chunks in the sweep

    if (tid < 128) minb[tid] = 0x7F800000;  // +inf (positive-float-as-int ordering)

    // Staging: thread covers LDS bytes {tid*16 + i*4096} per operand.
    //   row = (tid>>2) + i*64, granule = tid&3  (linear, no swizzle).
    const int srow = tid >> 2;                     // 0..63
    const int sg   = tid & 3;
    const unsigned short* aSrc0 = Abf + (size_t)(m0  + srow) * D_DIM + sg * 8;
    const unsigned short* bSrc0 = Bbf + (size_t)(nb0 + srow) * D_DIM + sg * 8;
    char* const ldsA0 = (char*)&ldsA[0][0][0] + tid * 16;
    char* const ldsB0 = (char*)&ldsB[0][0][0] + tid * 16;

    auto STAGE = [&](int gg) {
        const int b_  = gg & 1;
        const int kc_ = (gg & 15) << 5;            // k offset (elements), 0..480
        const int nt_ = gg >> 4;                   // code tile
        const unsigned short* as_ = aSrc0 + kc_;
        const unsigned short* bs_ = bSrc0 + (size_t)nt_ * (128 * D_DIM) + kc_;
        char* ad = ldsA0 + b_ * 8192;
        char* bd = ldsB0 + b_ * 8192;
        #pragma unroll
        for (int i = 0; i < 2; ++i) {
            gload_lds16(as_ + (size_t)i * (64 * D_DIM), ad + i * 4096);
            gload_lds16(bs_ + (size_t)i * (64 * D_DIM), bd + i * 4096);
        }
    };

    STAGE(0);
    __syncthreads();   // buf0 ready

    for (int nt = 0; nt < NT; ++nt) {
        // codebook norms for this tile straight into registers (consumed in epilogue)
        float s2r[4];
        #pragma unroll
        for (int nj = 0; nj < 4; ++nj)
            s2r[nj] = s2[nb0 + (nt << 7) + wn + nj * 16 + col];

        f32x4 acc[4][4];
        #pragma unroll
        for (int mi = 0; mi < 4; ++mi)
            #pragma unroll
            for (int nj = 0; nj < 4; ++nj) acc[mi][nj] = (f32x4){0.f, 0.f, 0.f, 0.f};

        #pragma unroll 2
        for (int t = 0; t < 16; ++t) {
            const int g = (nt << 4) + t;
            if (g + 1 < G) STAGE(g + 1);          // prefetch next chunk (other buffer)
            const int b = t & 1;                  // == g&1 (nt*16 is even)
            bf16x8 af[4], bfr[4];
            #pragma unroll
            for (int mi = 0; mi < 4; ++mi)
                af[mi] = *(const bf16x8*)&ldsA[b][wm + mi * 16 + col][q8 * 8];
            #pragma unroll
            for (int nj = 0; nj < 4; ++nj)
                bfr[nj] = *(const bf16x8*)&ldsB[b][wn + nj * 16 + col][q8 * 8];
            #pragma unroll
            for (int mi = 0; mi < 4; ++mi)
                #pragma unroll
                for (int nj = 0; nj < 4; ++nj)
                    acc[mi][nj] = __builtin_amdgcn_mfma_f32_16x16x32_bf16(
                        af[mi], bfr[nj], acc[mi][nj], 0, 0, 0);
            __syncthreads();   // drain prefetch + all reads of buf b done
        }

        // pass 1: settle per-row tile min into minb; keep this wave's per-row tile min
        // in registers for pass-2 pruning.
        float vt[4][4];
        #pragma unroll
        for (int mi = 0; mi < 4; ++mi) {
            #pragma unroll
            for (int rg = 0; rg < 4; ++rg) {
                float v = 3e38f;
                #pragma unroll
                for (int nj = 0; nj < 4; ++nj) {
                    float sc = 0.5f + fmaf(-2.0f, acc[mi][nj][rg], s2r[nj]);
                    v = fminf(v, sc);
                }
                #pragma unroll
                for (int off = 1; off < 16; off <<= 1)
                    v = fminf(v, __shfl_xor(v, off, 64));
                vt[mi][rg] = v;
                if (col == 0)
                    atomicMin(&minb[wm + mi * 16 + q8 * 4 + rg], __float_as_int(v));
            }
        }
        __syncthreads();

        // pass 2: emit candidates within THETA of running min. Whole (mi,rg) groups are
        // skipped when this wave's tile-min can't reach the band (common case).
        const int cbase = nb0 + (nt << 7) + wn;
        #pragma unroll
        for (int mi = 0; mi < 4; ++mi) {
            #pragma unroll
            for (int rg = 0; rg < 4; ++rg) {
                const int rl = wm + mi * 16 + q8 * 4 + rg;
                const float m = __int_as_float(minb[rl]);
                if (vt[mi][rg] > m + THETA) continue;
                #pragma unroll
                for (int nj = 0; nj < 4; ++nj) {
                    float sc = 0.5f + fmaf(-2.0f, acc[mi][nj][rg], s2r[nj]);
                    if (sc <= m + THETA) {
                        const int grow = m0 + rl;
                        unsigned p = atomicAdd(&cnt[grow], 1u);
                        if (p < 32u) cand[(size_t)grow * 32 + p] = (unsigned)(cbase + nj * 16 + col);
                    }
                }
            }
        }
        // no trailing barrier needed: minb is monotone (emission stays a superset of
        // any-winner set) and the next chunk's barriers re-sync before minb is touched.
    }
}

// ---------------- refine: exact f64 dot + numpy-grid f32 score over candidates ----------------
__global__ __launch_bounds__(256)
void k_refine(const float* __restrict__ x, const float* __restrict__ emb,
              const float* __restrict__ s1, const float* __restrict__ s2,
              const unsigned* __restrict__ cnt, const unsigned* __restrict__ cand,
              float* __restrict__ idx_out, int N, int K) {
    const int lane = threadIdx.x & 63;
    const int wgid = blockIdx.x * 4 + (threadIdx.x >> 6);
    const int row0 = wgid * 32;
    for (int rr = 0; rr < 32; ++rr) {
        int row = row0 + rr;
        if (row >= N) return;
        const float* xr = x + (size_t)row * D_DIM;
        float4 xa = *(const float4*)(xr + lane * 8);
        float4 xb = *(const float4*)(xr + lane * 8 + 4);
        unsigned c = cnt[row];
        float s1r = s1[row];
        float bs = 3e38f;
        int bi = 0;
        bool have = false;
        if (c >= 1u && c <= 32u) {
            for (unsigned i = 0; i < c; ++i) {
                int code = (int)cand[(size_t)row * 32 + i];
                const float* er = emb + (size_t)code * D_DIM;
                float4 ea = *(const float4*)(er + lane * 8);
                float4 eb = *(const float4*)(er + lane * 8 + 4);
                double d = 0.0;
                d = fma((double)xa.x, (double)ea.x, d);
                d = fma((double)xa.y, (double)ea.y, d);
                d = fma((double)xa.z, (double)ea.z, d);
                d = fma((double)xa.w, (double)ea.w, d);
                d = fma((double)xb.x, (double)eb.x, d);
                d = fma((double)xb.y, (double)eb.y, d);
                d = fma((double)xb.z, (double)eb.z, d);
                d = fma((double)xb.w, (double)eb.w, d);
                #pragma unroll
                for (int off = 32; off > 0; off >>= 1) d += __shfl_down(d, off, 64);
                if (lane == 0) {
                    float tt = __fadd_rn(s1r, s2[code]);
                    float u  = __fmul_rn(2.0f, (float)d);
                    float s  = __fadd_rn(tt, -u);
                    if (!have || s < bs || (s == bs && code < bi)) { bs = s; bi = code; have = true; }
                }
            }
        } else {
            // overflow (or impossible zero) -> exact full scan
            for (int code = 0; code < K; ++code) {
                const float* er = emb + (size_t)code * D_DIM;
                float4 ea = *(const float4*)(er + lane * 8);
                float4 eb = *(const float4*)(er + lane * 8 + 4);
                double d = 0.0;
                d = fma((double)xa.x, (double)ea.x, d);
                d = fma((double)xa.y, (double)ea.y, d);
                d = fma((double)xa.z, (double)ea.z, d);
                d = fma((double)xa.w, (double)ea.w, d);
                d = fma((double)xb.x, (double)eb.x, d);
                d = fma((double)xb.y, (double)eb.y, d);
                d = fma((double)xb.z, (double)eb.z, d);
                d = fma((double)xb.w, (double)eb.w, d);
                #pragma unroll
                for (int off = 32; off > 0; off >>= 1) d += __shfl_down(d, off, 64);
                if (lane == 0) {
                    float tt = __fadd_rn(s1r, s2[code]);
                    float u  = __fmul_rn(2.0f, (float)d);
                    float s  = __fadd_rn(tt, -u);
                    if (!have || s < bs) { bs = s; bi = code; have = true; }
                }
            }
        }
        if (lane == 0) idx_out[row] = (float)bi;
    }
}

// ---------------- fallback: R3's passing f64 argmin (used if ws too small) ----------------
constexpr int BM = 64;
constexpr int BN = 128;
constexpr int BD = 32;
constexpr int TX = 16;
struct TileView { float xs[BD][BM + 4]; float es[BD][BN + 4]; };
struct RedView  { float s[BM][TX + 1]; int i[BM][TX + 1]; };

__global__ __launch_bounds__(256)
void k_argmin(const float* __restrict__ x, const float* __restrict__ emb,
              const float* __restrict__ s1, const float* __restrict__ s2,
              float* __restrict__ idx_out, int N, int K) {
    __shared__ alignas(16) char smem_raw[sizeof(TileView) > sizeof(RedView)
                                         ? sizeof(TileView) : sizeof(RedView)];
    TileView& t = *reinterpret_cast<TileView*>(smem_raw);
    RedView&  r = *reinterpret_cast<RedView*>(smem_raw);
    __shared__ float ces[BN];
    const int tid = threadIdx.x;
    const int tx = tid & 15;
    const int ty = tid >> 4;
    const int rowBase = blockIdx.x * BM;
    if (rowBase >= N) return;
    float rs1[4];
    #pragma unroll
    for (int i = 0; i < 4; ++i) rs1[i] = s1[rowBase + 4 * ty + i];
    float bs[4] = {3.0e38f, 3.0e38f, 3.0e38f, 3.0e38f};
    int   bi[4] = {0, 0, 0, 0};
    for (int nt = 0; nt < K; nt += BN) {
        double acc[4][8];
        #pragma unroll
        for (int i = 0; i < 4; ++i)
            #pragma unroll
            for (int j = 0; j < 8; ++j) acc[i][j] = 0.0;
        for (int dc = 0; dc < D_DIM; dc += BD) {
            __syncthreads();
            #pragma unroll
            for (int i = 0; i < 2; ++i) {
                int q = tid + i * 256;
                int rr = q >> 3, c4 = q & 7;
                float4 v = *(const float4*)(x + (size_t)(rowBase + rr) * D_DIM + dc + 4 * c4);
                t.xs[4 * c4 + 0][rr] = v.x; t.xs[4 * c4 + 1][rr] = v.y;
                t.xs[4 * c4 + 2][rr] = v.z; t.xs[4 * c4 + 3][rr] = v.w;
            }
            #pragma unroll
            for (int i = 0; i < 4; ++i) {
                int q = tid + i * 256;
                int rr = q >> 3, c4 = q & 7;
                float4 v = *(const float4*)(emb + (size_t)(nt + rr) * D_DIM + dc + 4 * c4);
                t.es[4 * c4 + 0][rr] = v.x; t.es[4 * c4 + 1][rr] = v.y;
                t.es[4 * c4 + 2][rr] = v.z; t.es[4 * c4 + 3][rr] = v.w;
            }
            if (dc == 0 && tid < BN) ces[tid] = s2[nt + tid];
            __syncthreads();
            #pragma unroll
            for (int d = 0; d < BD; ++d) {
                float4 af = *(const float4*)&t.xs[d][4 * ty];
                float4 b0 = *(const float4*)&t.es[d][4 * tx];
                float4 b1 = *(const float4*)&t.es[d][64 + 4 * tx];
                double a[4] = {af.x, af.y, af.z, af.w};
                double b[8] = {b0.x, b0.y, b0.z, b0.w, b1.x, b1.y, b1.z, b1.w};
                #pragma unroll
                for (int i = 0; i < 4; ++i)
                    #pragma unroll
                    for (int j = 0; j < 8; ++j)
                        acc[i][j] = fma(a[i], b[j], acc[i][j]);
            }
        }
        #pragma unroll
        for (int j = 0; j < 8; ++j) {
            int cc = (j < 4) ? (4 * tx + j) : (64 + 4 * tx + (j - 4));
            int code = nt + cc;
            float ce = ces[cc];
            #pragma unroll
            for (int i = 0; i < 4; ++i) {
                float tt = __fadd_rn(rs1[i], ce);
                float u  = __fmul_rn(2.0f, (float)acc[i][j]);
                float s  = __fadd_rn(tt, -u);
                if (s < bs[i]) { bs[i] = s; bi[i] = code; }
            }
        }
    }
    __syncthreads();
    #pragma unroll
    for (int i = 0; i < 4; ++i) { r.s[4 * ty + i][tx] = bs[i]; r.i[4 * ty + i][tx] = bi[i]; }
    __syncthreads();
    if (tid < BM) {
        float best = r.s[tid][0];
        int bidx = r.i[tid][0];
        #pragma unroll
        for (int tt = 1; tt < TX; ++tt) {
            float s = r.s[tid][tt];
            int ii = r.i[tid][tt];
            if (s < best || (s == best && ii < bidx)) { best = s; bidx = ii; }
        }
        idx_out[rowBase + tid] = (float)bidx;
    }
}

// ---------------- gather + straight-through output + loss ----------------
__global__ __launch_bounds__(128)
void k_gather(const float* __restrict__ x, const float* __restrict__ emb,
              const float* __restrict__ idx_f, float* __restrict__ out,
              float* __restrict__ loss_ptr, float loss_scale) {
    const int row = blockIdx.x;
    const int t = threadIdx.x;
    const int idx = (int)idx_f[row];
    const float4 xv = *(const float4*)(x + (size_t)row * D_DIM + 4 * t);
    const float4 ev = *(const float4*)(emb + (size_t)idx * D_DIM + 4 * t);
    float4 o;
    o.x = xv.x * 0.95f + (ev.x - xv.x) * 0.05f;
    o.y = xv.y * 0.95f + (ev.y - xv.y) * 0.05f;
    o.z = xv.z * 0.95f + (ev.z - xv.z) * 0.05f;
    o.w = xv.w * 0.95f + (ev.w - xv.w) * 0.05f;
    *(float4*)(out + (size_t)row * D_DIM + 4 * t) = o;
    float d0 = ev.x - xv.x, d1 = ev.y - xv.y, d2 = ev.z - xv.z, d3 = ev.w - xv.w;
    float ls = d0 * d0 + d1 * d1 + d2 * d2 + d3 * d3;
    #pragma unroll
    for (int off = 32; off > 0; off >>= 1) ls += __shfl_down(ls, off, 64);
    __shared__ float wsum[2];
    if ((t & 63) == 0) wsum[t >> 6] = ls;
    __syncthreads();
    if (t == 0) atomicAdd(loss_ptr, (wsum[0] + wsum[1]) * loss_scale);
}

extern "C" void kernel_launch(void* const* d_in, const int* in_sizes, int n_in,
                              void* d_out, int out_size, void* d_ws, size_t ws_size,
                              hipStream_t stream) {
    const float* x   = (const float*)d_in[0];
    const float* emb = (const float*)d_in[1];
    const int N = in_sizes[0] / D_DIM;   // 32768
    const int K = in_sizes[1] / D_DIM;   // 8192

    float* out      = (float*)d_out;
    float* idx_out  = out + (size_t)N * D_DIM;
    float* loss_ptr = idx_out + N;

    char* ws = (char*)d_ws;
    size_t offA    = 0;
    size_t offB    = offA + (size_t)N * D_DIM * 2;
    size_t offS2   = offB + (size_t)K * D_DIM * 2;
    size_t offS1   = offS2 + (size_t)K * 4;
    size_t offCnt  = offS1 + (size_t)N * 4;
    size_t offCand = offCnt + (size_t)N * 4;
    size_t need    = offCand + (size_t)N * 32 * 4;

    const float loss_scale = 1.25f / ((float)N * (float)D_DIM);

    bool fast = (ws_size >= need) && (N % 256 == 0) && (K % 512 == 0);
    if (fast) {
        unsigned short* A = (unsigned short*)(ws + offA);
        unsigned short* B = (unsigned short*)(ws + offB);
        float* s2    = (float*)(ws + offS2);
        float* s1    = (float*)(ws + offS1);
        unsigned* cnt  = (unsigned*)(ws + offCnt);
        unsigned* cand = (unsigned*)(ws + offCand);

        k_norms<<<(K + 255) / 256, 256, 0, stream>>>(emb, s2, K, loss_ptr, nullptr);
        k_norms<<<(N + 255) / 256, 256, 0, stream>>>(x, s1, N, nullptr, cnt);
        k_cvt_bf16<<<(N * (D_DIM / 8)) / 256, 256, 0, stream>>>(x, A, (size_t)N * (D_DIM / 8));
        k_cvt_bf16<<<(K * (D_DIM / 8)) / 256, 256, 0, stream>>>(emb, B, (size_t)K * (D_DIM / 8));
        k_score<<<dim3(N / 128, 4), 256, 0, stream>>>(A, B, s2, cnt, cand, N, K);
        k_refine<<<N / 128, 256, 0, stream>>>(x, emb, s1, s2, cnt, cand, idx_out, N, K);
    } else {
        float* s2 = (float*)d_ws;
        float* s1 = s2 + K;
        k_norms<<<(K + 255) / 256, 256, 0, stream>>>(emb, s2, K, loss_ptr, nullptr);
        k_norms<<<(N + 255) / 256, 256, 0, stream>>>(x, s1, N, nullptr, nullptr);
        k_argmin<<<N / BM, 256, 0, stream>>>(x, emb, s1, s2, idx_out, N, K);
    }
    k_gather<<<N, 128, 0, stream>>>(x, emb, idx_out, out, loss_ptr, loss_scale);
}

// Round 5
// 1151.118 us; speedup vs baseline: 15.8950x; 15.8950x over previous
//
#include <hip/hip_runtime.h>
#include <math.h>

#define D_DIM 512

typedef __attribute__((ext_vector_type(8))) short bf16x8;
typedef __attribute__((ext_vector_type(4))) float f32x4;

#define AS1 __attribute__((address_space(1)))
#define AS3 __attribute__((address_space(3)))

// async global->LDS, 16B per lane. LDS dest must be wave-uniform base + lane*16.
__device__ __forceinline__ void gload_lds16(const void* g, void* l) {
    __builtin_amdgcn_global_load_lds((AS1 const void*)g, (AS3 void*)l, 16, 0, 0);
}

// ---------- numpy pairwise-sum replica for sum(v*v) over 512 contiguous floats ----------
__device__ __forceinline__ float pw128_sq(const float* __restrict__ a) {
    float r[8];
    #pragma unroll
    for (int j = 0; j < 8; ++j) r[j] = __fmul_rn(a[j], a[j]);
    #pragma unroll
    for (int i = 8; i < 128; i += 8)
        #pragma unroll
        for (int j = 0; j < 8; ++j) r[j] = __fadd_rn(r[j], __fmul_rn(a[i + j], a[i + j]));
    float s01 = __fadd_rn(r[0], r[1]);
    float s23 = __fadd_rn(r[2], r[3]);
    float s45 = __fadd_rn(r[4], r[5]);
    float s67 = __fadd_rn(r[6], r[7]);
    return __fadd_rn(__fadd_rn(s01, s23), __fadd_rn(s45, s67));
}
__device__ __forceinline__ float rownorm512(const float* __restrict__ row) {
    float b0 = pw128_sq(row);
    float b1 = pw128_sq(row + 128);
    float b2 = pw128_sq(row + 256);
    float b3 = pw128_sq(row + 384);
    return __fadd_rn(__fadd_rn(b0, b1), __fadd_rn(b2, b3));
}

// ---------------- norms kernel (numpy-faithful f32) + optional zero of loss / cnt ----------------
__global__ void k_norms(const float* __restrict__ a, float* __restrict__ out, int nrows,
                        float* __restrict__ loss_ptr, unsigned* __restrict__ cnt) {
    int r = blockIdx.x * blockDim.x + threadIdx.x;
    if (r == 0 && loss_ptr) *loss_ptr = 0.0f;
    if (r >= nrows) return;
    if (cnt) cnt[r] = 0u;
    out[r] = rownorm512(a + (size_t)r * D_DIM);
}

// ---------------- f32 -> bf16 (RNE) convert, 8 elems/thread ----------------
__global__ void k_cvt_bf16(const float* __restrict__ src, unsigned short* __restrict__ dst,
                           size_t n8) {
    size_t i = blockIdx.x * (size_t)blockDim.x + threadIdx.x;
    if (i >= n8) return;
    const float4* s = (const float4*)(src + i * 8);
    float4 v0 = s[0], v1 = s[1];
    float vv[8] = {v0.x, v0.y, v0.z, v0.w, v1.x, v1.y, v1.z, v1.w};
    unsigned u[8];
    #pragma unroll
    for (int j = 0; j < 8; ++j) {
        unsigned b = __float_as_uint(vv[j]);
        b = b + 0x7FFFu + ((b >> 16) & 1u);
        u[j] = b >> 16;
    }
    uint4 w;
    w.x = u[0] | (u[1] << 16);
    w.y = u[2] | (u[3] << 16);
    w.z = u[4] | (u[5] << 16);
    w.w = u[6] | (u[7] << 16);
    *(uint4*)(dst + i * 8) = w;
}

// ---------------- MFMA filter sweep (R1 structure: verified 488us) ----------------
// grid (128 Mtiles, 2 N-halves), 512 threads (8 waves as 4m x 2n, wave-tile 64x128).
// Block tile: 256 rows x 256 codes per nt step, BK=64, double-buffered LDS filled by
// global_load_lds (linear dest, inverse-XOR-swizzled source; XOR-swizzled ds_read).
// Running per-row min in LDS, candidate emission s' <= m + THETA (safe superset of all
// possible grid-argmin winners).
#define THETA 4.0e-4f

__global__ __launch_bounds__(512, 2)
void k_score(const unsigned short* __restrict__ Abf, const unsigned short* __restrict__ Bbf,
             const float* __restrict__ s2, unsigned* __restrict__ cnt,
             unsigned* __restrict__ cand, int N, int K) {
    // [buf][A=0/B=1][256 rows][64 k-elems], 128 KiB. Granule g (16B) of row r holds
    // k-slot (g ^ (r&7)) -> stride-128B rows read conflict-free (<=2-way).
    __shared__ unsigned short lds[2][2][256][64];
    __shared__ int minb[256];

    const int tid  = threadIdx.x;
    const int lane = tid & 63;
    const int wid  = tid >> 6;            // 0..7
    const int wm   = (wid >> 1) * 64;     // 0,64,128,192
    const int wn   = (wid & 1) * 128;     // 0,128
    const int col  = lane & 15;
    const int q8   = lane >> 4;           // 0..3
    const int xg   = col & 7;             // == row&7 for every fragment row we read
    const int m0   = blockIdx.x * 256;
    const int nhalf = K >> 1;             // 4096
    const int nb0  = blockIdx.y * nhalf;
    const int NT   = nhalf >> 8;          // 16 code tiles of 256
    const int G    = NT * 8;              // total BK=64 chunks in the sweep

    if (tid < 256) minb[tid] = 0x7F800000;  // +inf (positive-float-as-int ordering)

    // Staging geometry: thread covers LDS bytes {tid*16 + i*8192}, i=0..3 per operand.
    //   row r = srow + i*64, granule = tid&7, so source k-slot = (tid&7) ^ (srow&7)
    //   (i*64 == 0 mod 8 keeps the slot i-invariant).
    const int srow  = tid >> 3;                    // 0..63
    const int sslot = (tid & 7) ^ (srow & 7);      // inverse swizzle on the SOURCE side
    const unsigned short* aSrc0 = Abf + (size_t)(m0  + srow) * D_DIM + sslot * 8;
    const unsigned short* bSrc0 = Bbf + (size_t)(nb0 + srow) * D_DIM + sslot * 8;
    char* const ldsA0 = (char*)&lds[0][0][0][0] + tid * 16;
    char* const ldsB0 = (char*)&lds[0][1][0][0] + tid * 16;

    auto STAGE = [&](int gg) {
        const int b_  = gg & 1;
        const int kc_ = (gg & 7) << 6;             // k offset, 0..448
        const int nt_ = gg >> 3;                   // code tile
        const unsigned short* as_ = aSrc0 + kc_;
        const unsigned short* bs_ = bSrc0 + (size_t)nt_ * (256 * D_DIM) + kc_;
        char* ad = ldsA0 + b_ * 65536;
        char* bd = ldsB0 + b_ * 65536;
        #pragma unroll
        for (int i = 0; i < 4; ++i) {
            gload_lds16(as_ + (size_t)i * (64 * D_DIM), ad + i * 8192);
            gload_lds16(bs_ + (size_t)i * (64 * D_DIM), bd + i * 8192);
        }
    };

    STAGE(0);
    __syncthreads();   // compiler emits vmcnt(0) drain -> buf0 ready

    for (int nt = 0; nt < NT; ++nt) {
        // codebook norms for this tile straight into registers (L2-resident, hidden
        // under the chunk loop; only consumed in the epilogue)
        float s2r[8];
        #pragma unroll
        for (int nj = 0; nj < 8; ++nj)
            s2r[nj] = s2[nb0 + (nt << 8) + wn + nj * 16 + col];

        f32x4 acc[4][8];
        #pragma unroll
        for (int mi = 0; mi < 4; ++mi)
            #pragma unroll
            for (int nj = 0; nj < 8; ++nj) acc[mi][nj] = (f32x4){0.f, 0.f, 0.f, 0.f};

        #pragma unroll 2
        for (int t = 0; t < 8; ++t) {
            const int g = (nt << 3) + t;
            if (g + 1 < G) STAGE(g + 1);          // prefetch next chunk (other buffer)
            const int b = t & 1;                  // == g&1 (nt*8 is even)
            const char* baseA = (const char*)&lds[b][0][0][0];
            const char* baseB = (const char*)&lds[b][1][0][0];
            const int rowA = (wm + col) << 7;     // byte offset of this lane's A row
            const int rowB = (wn + col) << 7;
            #pragma unroll
            for (int ks = 0; ks < 2; ++ks) {
                const int gb = ((((ks << 2) | q8) ^ xg) << 4);   // swizzled granule byte
                bf16x8 af[4], bfr[8];
                #pragma unroll
                for (int mi = 0; mi < 4; ++mi)
                    af[mi] = *(const bf16x8*)(baseA + rowA + mi * 2048 + gb);
                #pragma unroll
                for (int nj = 0; nj < 8; ++nj)
                    bfr[nj] = *(const bf16x8*)(baseB + rowB + nj * 2048 + gb);
                #pragma unroll
                for (int mi = 0; mi < 4; ++mi)
                    #pragma unroll
                    for (int nj = 0; nj < 8; ++nj)
                        acc[mi][nj] = __builtin_amdgcn_mfma_f32_16x16x32_bf16(
                            af[mi], bfr[nj], acc[mi][nj], 0, 0, 0);
            }
            __syncthreads();   // lgkm drain for ds_reads + vmcnt drain for the prefetch
        }

        // pass 1: settle per-row tile min into minb; keep this wave's per-row tile min
        // in registers for pass-2 pruning.
        float vt[4][4];
        #pragma unroll
        for (int mi = 0; mi < 4; ++mi) {
            #pragma unroll
            for (int rg = 0; rg < 4; ++rg) {
                float v = 3e38f;
                #pragma unroll
                for (int nj = 0; nj < 8; ++nj) {
                    float sc = 0.5f + fmaf(-2.0f, acc[mi][nj][rg], s2r[nj]);
                    v = fminf(v, sc);
                }
                #pragma unroll
                for (int off = 1; off < 16; off <<= 1)
                    v = fminf(v, __shfl_xor(v, off, 64));
                vt[mi][rg] = v;
                if (col == 0)
                    atomicMin(&minb[wm + mi * 16 + q8 * 4 + rg], __float_as_int(v));
            }
        }
        __syncthreads();

        // pass 2: emit candidates within THETA of running min. Whole (mi,rg) groups are
        // skipped when this wave's tile-min can't reach the band (common case).
        const int cbase = nb0 + (nt << 8) + wn;
        #pragma unroll
        for (int mi = 0; mi < 4; ++mi) {
            #pragma unroll
            for (int rg = 0; rg < 4; ++rg) {
                const int rl = wm + mi * 16 + q8 * 4 + rg;
                const float m = __int_as_float(minb[rl]);
                if (vt[mi][rg] > m + THETA) continue;
                #pragma unroll
                for (int nj = 0; nj < 8; ++nj) {
                    float sc = 0.5f + fmaf(-2.0f, acc[mi][nj][rg], s2r[nj]);
                    if (sc <= m + THETA) {
                        const int grow = m0 + rl;
                        unsigned p = atomicAdd(&cnt[grow], 1u);
                        if (p < 32u) cand[(size_t)grow * 32 + p] = (unsigned)(cbase + nj * 16 + col);
                    }
                }
            }
        }
        // no trailing barrier needed: minb is monotone (emission stays a superset of
        // any-winner set) and the next chunk's barriers re-sync before minb is touched.
    }
}

// ---------------- refine: exact f64 dot + numpy-grid f32 score over candidates ----------------
// TLP fix: 2 rows per wave (was 32). Grid N/8 blocks of 4 waves -> 16k waves, 0 LDS,
// low VGPR -> ~8 blocks/CU resident; the per-candidate latency chain (load -> f64 dot
// -> shuffle reduce) is hidden by wave multiplexing instead of serialized 32x per wave.
__global__ __launch_bounds__(256)
void k_refine(const float* __restrict__ x, const float* __restrict__ emb,
              const float* __restrict__ s1, const float* __restrict__ s2,
              const unsigned* __restrict__ cnt, const unsigned* __restrict__ cand,
              float* __restrict__ idx_out, int N, int K) {
    const int lane = threadIdx.x & 63;
    const int wgid = blockIdx.x * 4 + (threadIdx.x >> 6);
    const int row0 = wgid * 2;
    for (int rr = 0; rr < 2; ++rr) {
        int row = row0 + rr;
        if (row >= N) return;
        const float* xr = x + (size_t)row * D_DIM;
        float4 xa = *(const float4*)(xr + lane * 8);
        float4 xb = *(const float4*)(xr + lane * 8 + 4);
        unsigned c = cnt[row];
        float s1r = s1[row];
        float bs = 3e38f;
        int bi = 0;
        bool have = false;
        if (c >= 1u && c <= 32u) {
            for (unsigned i = 0; i < c; ++i) {
                int code = (int)cand[(size_t)row * 32 + i];
                const float* er = emb + (size_t)code * D_DIM;
                float4 ea = *(const float4*)(er + lane * 8);
                float4 eb = *(const float4*)(er + lane * 8 + 4);
                double d = 0.0;
                d = fma((double)xa.x, (double)ea.x, d);
                d = fma((double)xa.y, (double)ea.y, d);
                d = fma((double)xa.z, (double)ea.z, d);
                d = fma((double)xa.w, (double)ea.w, d);
                d = fma((double)xb.x, (double)eb.x, d);
                d = fma((double)xb.y, (double)eb.y, d);
                d = fma((double)xb.z, (double)eb.z, d);
                d = fma((double)xb.w, (double)eb.w, d);
                #pragma unroll
                for (int off = 32; off > 0; off >>= 1) d += __shfl_down(d, off, 64);
                if (lane == 0) {
                    float tt = __fadd_rn(s1r, s2[code]);
                    float u  = __fmul_rn(2.0f, (float)d);
                    float s  = __fadd_rn(tt, -u);
                    if (!have || s < bs || (s == bs && code < bi)) { bs = s; bi = code; have = true; }
                }
            }
        } else {
            // overflow (or impossible zero) -> exact full scan
            for (int code = 0; code < K; ++code) {
                const float* er = emb + (size_t)code * D_DIM;
                float4 ea = *(const float4*)(er + lane * 8);
                float4 eb = *(const float4*)(er + lane * 8 + 4);
                double d = 0.0;
                d = fma((double)xa.x, (double)ea.x, d);
                d = fma((double)xa.y, (double)ea.y, d);
                d = fma((double)xa.z, (double)ea.z, d);
                d = fma((double)xa.w, (double)ea.w, d);
                d = fma((double)xb.x, (double)eb.x, d);
                d = fma((double)xb.y, (double)eb.y, d);
                d = fma((double)xb.z, (double)eb.z, d);
                d = fma((double)xb.w, (double)eb.w, d);
                #pragma unroll
                for (int off = 32; off > 0; off >>= 1) d += __shfl_down(d, off, 64);
                if (lane == 0) {
                    float tt = __fadd_rn(s1r, s2[code]);
                    float u  = __fmul_rn(2.0f, (float)d);
                    float s  = __fadd_rn(tt, -u);
                    if (!have || s < bs) { bs = s; bi = code; have = true; }
                }
            }
        }
        if (lane == 0) idx_out[row] = (float)bi;
    }
}

// ---------------- fallback: R3's passing f64 argmin (used if ws too small) ----------------
constexpr int BM = 64;
constexpr int BN = 128;
constexpr int BD = 32;
constexpr int TX = 16;
struct TileView { float xs[BD][BM + 4]; float es[BD][BN + 4]; };
struct RedView  { float s[BM][TX + 1]; int i[BM][TX + 1]; };

__global__ __launch_bounds__(256)
void k_argmin(const float* __restrict__ x, const float* __restrict__ emb,
              const float* __restrict__ s1, const float* __restrict__ s2,
              float* __restrict__ idx_out, int N, int K) {
    __shared__ alignas(16) char smem_raw[sizeof(TileView) > sizeof(RedView)
                                         ? sizeof(TileView) : sizeof(RedView)];
    TileView& t = *reinterpret_cast<TileView*>(smem_raw);
    RedView&  r = *reinterpret_cast<RedView*>(smem_raw);
    __shared__ float ces[BN];
    const int tid = threadIdx.x;
    const int tx = tid & 15;
    const int ty = tid >> 4;
    const int rowBase = blockIdx.x * BM;
    if (rowBase >= N) return;
    float rs1[4];
    #pragma unroll
    for (int i = 0; i < 4; ++i) rs1[i] = s1[rowBase + 4 * ty + i];
    float bs[4] = {3.0e38f, 3.0e38f, 3.0e38f, 3.0e38f};
    int   bi[4] = {0, 0, 0, 0};
    for (int nt = 0; nt < K; nt += BN) {
        double acc[4][8];
        #pragma unroll
        for (int i = 0; i < 4; ++i)
            #pragma unroll
            for (int j = 0; j < 8; ++j) acc[i][j] = 0.0;
        for (int dc = 0; dc < D_DIM; dc += BD) {
            __syncthreads();
            #pragma unroll
            for (int i = 0; i < 2; ++i) {
                int q = tid + i * 256;
                int rr = q >> 3, c4 = q & 7;
                float4 v = *(const float4*)(x + (size_t)(rowBase + rr) * D_DIM + dc + 4 * c4);
                t.xs[4 * c4 + 0][rr] = v.x; t.xs[4 * c4 + 1][rr] = v.y;
                t.xs[4 * c4 + 2][rr] = v.z; t.xs[4 * c4 + 3][rr] = v.w;
            }
            #pragma unroll
            for (int i = 0; i < 4; ++i) {
                int q = tid + i * 256;
                int rr = q >> 3, c4 = q & 7;
                float4 v = *(const float4*)(emb + (size_t)(nt + rr) * D_DIM + dc + 4 * c4);
                t.es[4 * c4 + 0][rr] = v.x; t.es[4 * c4 + 1][rr] = v.y;
                t.es[4 * c4 + 2][rr] = v.z; t.es[4 * c4 + 3][rr] = v.w;
            }
            if (dc == 0 && tid < BN) ces[tid] = s2[nt + tid];
            __syncthreads();
            #pragma unroll
            for (int d = 0; d < BD; ++d) {
                float4 af = *(const float4*)&t.xs[d][4 * ty];
                float4 b0 = *(const float4*)&t.es[d][4 * tx];
                float4 b1 = *(const float4*)&t.es[d][64 + 4 * tx];
                double a[4] = {af.x, af.y, af.z, af.w};
                double b[8] = {b0.x, b0.y, b0.z, b0.w, b1.x, b1.y, b1.z, b1.w};
                #pragma unroll
                for (int i = 0; i < 4; ++i)
                    #pragma unroll
                    for (int j = 0; j < 8; ++j)
                        acc[i][j] = fma(a[i], b[j], acc[i][j]);
            }
        }
        #pragma unroll
        for (int j = 0; j < 8; ++j) {
            int cc = (j < 4) ? (4 * tx + j) : (64 + 4 * tx + (j - 4));
            int code = nt + cc;
            float ce = ces[cc];
            #pragma unroll
            for (int i = 0; i < 4; ++i) {
                float tt = __fadd_rn(rs1[i], ce);
                float u  = __fmul_rn(2.0f, (float)acc[i][j]);
                float s  = __fadd_rn(tt, -u);
                if (s < bs[i]) { bs[i] = s; bi[i] = code; }
            }
        }
    }
    __syncthreads();
    #pragma unroll
    for (int i = 0; i < 4; ++i) { r.s[4 * ty + i][tx] = bs[i]; r.i[4 * ty + i][tx] = bi[i]; }
    __syncthreads();
    if (tid < BM) {
        float best = r.s[tid][0];
        int bidx = r.i[tid][0];
        #pragma unroll
        for (int tt = 1; tt < TX; ++tt) {
            float s = r.s[tid][tt];
            int ii = r.i[tid][tt];
            if (s < best || (s == best && ii < bidx)) { best = s; bidx = ii; }
        }
        idx_out[rowBase + tid] = (float)bidx;
    }
}

// ---------------- gather + straight-through output + loss ----------------
__global__ __launch_bounds__(128)
void k_gather(const float* __restrict__ x, const float* __restrict__ emb,
              const float* __restrict__ idx_f, float* __restrict__ out,
              float* __restrict__ loss_ptr, float loss_scale) {
    const int row = blockIdx.x;
    const int t = threadIdx.x;
    const int idx = (int)idx_f[row];
    const float4 xv = *(const float4*)(x + (size_t)row * D_DIM + 4 * t);
    const float4 ev = *(const float4*)(emb + (size_t)idx * D_DIM + 4 * t);
    float4 o;
    o.x = xv.x * 0.95f + (ev.x - xv.x) * 0.05f;
    o.y = xv.y * 0.95f + (ev.y - xv.y) * 0.05f;
    o.z = xv.z * 0.95f + (ev.z - xv.z) * 0.05f;
    o.w = xv.w * 0.95f + (ev.w - xv.w) * 0.05f;
    *(float4*)(out + (size_t)row * D_DIM + 4 * t) = o;
    float d0 = ev.x - xv.x, d1 = ev.y - xv.y, d2 = ev.z - xv.z, d3 = ev.w - xv.w;
    float ls = d0 * d0 + d1 * d1 + d2 * d2 + d3 * d3;
    #pragma unroll
    for (int off = 32; off > 0; off >>= 1) ls += __shfl_down(ls, off, 64);
    __shared__ float wsum[2];
    if ((t & 63) == 0) wsum[t >> 6] = ls;
    __syncthreads();
    if (t == 0) atomicAdd(loss_ptr, (wsum[0] + wsum[1]) * loss_scale);
}

extern "C" void kernel_launch(void* const* d_in, const int* in_sizes, int n_in,
                              void* d_out, int out_size, void* d_ws, size_t ws_size,
                              hipStream_t stream) {
    const float* x   = (const float*)d_in[0];
    const float* emb = (const float*)d_in[1];
    const int N = in_sizes[0] / D_DIM;   // 32768
    const int K = in_sizes[1] / D_DIM;   // 8192

    float* out      = (float*)d_out;
    float* idx_out  = out + (size_t)N * D_DIM;
    float* loss_ptr = idx_out + N;

    char* ws = (char*)d_ws;
    size_t offA    = 0;
    size_t offB    = offA + (size_t)N * D_DIM * 2;
    size_t offS2   = offB + (size_t)K * D_DIM * 2;
    size_t offS1   = offS2 + (size_t)K * 4;
    size_t offCnt  = offS1 + (size_t)N * 4;
    size_t offCand = offCnt + (size_t)N * 4;
    size_t need    = offCand + (size_t)N * 32 * 4;

    const float loss_scale = 1.25f / ((float)N * (float)D_DIM);

    bool fast = (ws_size >= need) && (N % 256 == 0) && (K % 512 == 0);
    if (fast) {
        unsigned short* A = (unsigned short*)(ws + offA);
        unsigned short* B = (unsigned short*)(ws + offB);
        float* s2    = (float*)(ws + offS2);
        float* s1    = (float*)(ws + offS1);
        unsigned* cnt  = (unsigned*)(ws + offCnt);
        unsigned* cand = (unsigned*)(ws + offCand);

        k_norms<<<(K + 255) / 256, 256, 0, stream>>>(emb, s2, K, loss_ptr, nullptr);
        k_norms<<<(N + 255) / 256, 256, 0, stream>>>(x, s1, N, nullptr, cnt);
        k_cvt_bf16<<<(N * (D_DIM / 8)) / 256, 256, 0, stream>>>(x, A, (size_t)N * (D_DIM / 8));
        k_cvt_bf16<<<(K * (D_DIM / 8)) / 256, 256, 0, stream>>>(emb, B, (size_t)K * (D_DIM / 8));
        k_score<<<dim3(N / 256, 2), 512, 0, stream>>>(A, B, s2, cnt, cand, N, K);
        k_refine<<<N / 8, 256, 0, stream>>>(x, emb, s1, s2, cnt, cand, idx_out, N, K);
    } else {
        float* s2 = (float*)d_ws;
        float* s1 = s2 + K;
        k_norms<<<(K + 255) / 256, 256, 0, stream>>>(emb, s2, K, loss_ptr, nullptr);
        k_norms<<<(N + 255) / 256, 256, 0, stream>>>(x, s1, N, nullptr, nullptr);
        k_argmin<<<N / BM, 256, 0, stream>>>(x, emb, s1, s2, idx_out, N, K);
    }
    k_gather<<<N, 128, 0, stream>>>(x, emb, idx_out, out, loss_ptr, loss_scale);
}

// Round 6
// 754.534 us; speedup vs baseline: 24.2495x; 1.5256x over previous
//
#include <hip/hip_runtime.h>
#include <math.h>

#define D_DIM 512

typedef __attribute__((ext_vector_type(8))) short bf16x8;
typedef __attribute__((ext_vector_type(4))) float f32x4;

#define AS1 __attribute__((address_space(1)))
#define AS3 __attribute__((address_space(3)))

// async global->LDS, 16B per lane. LDS dest must be wave-uniform base + lane*16.
__device__ __forceinline__ void gload_lds16(const void* g, void* l) {
    __builtin_amdgcn_global_load_lds((AS1 const void*)g, (AS3 void*)l, 16, 0, 0);
}

// ---------- numpy pairwise-sum replica for sum(v*v) over 512 contiguous floats ----------
// float4-vectorized; the __fmul_rn/__fadd_rn op sequence (8 accumulators, pairwise tail)
// is IDENTICAL to the scalar version -> bit-exact same result, 4x fewer load instrs.
__device__ __forceinline__ float pw128_sq(const float* __restrict__ a) {
    float4 v0 = *(const float4*)(a);
    float4 v1 = *(const float4*)(a + 4);
    float r[8];
    r[0] = __fmul_rn(v0.x, v0.x); r[1] = __fmul_rn(v0.y, v0.y);
    r[2] = __fmul_rn(v0.z, v0.z); r[3] = __fmul_rn(v0.w, v0.w);
    r[4] = __fmul_rn(v1.x, v1.x); r[5] = __fmul_rn(v1.y, v1.y);
    r[6] = __fmul_rn(v1.z, v1.z); r[7] = __fmul_rn(v1.w, v1.w);
    #pragma unroll
    for (int i = 8; i < 128; i += 8) {
        float4 u0 = *(const float4*)(a + i);
        float4 u1 = *(const float4*)(a + i + 4);
        r[0] = __fadd_rn(r[0], __fmul_rn(u0.x, u0.x));
        r[1] = __fadd_rn(r[1], __fmul_rn(u0.y, u0.y));
        r[2] = __fadd_rn(r[2], __fmul_rn(u0.z, u0.z));
        r[3] = __fadd_rn(r[3], __fmul_rn(u0.w, u0.w));
        r[4] = __fadd_rn(r[4], __fmul_rn(u1.x, u1.x));
        r[5] = __fadd_rn(r[5], __fmul_rn(u1.y, u1.y));
        r[6] = __fadd_rn(r[6], __fmul_rn(u1.z, u1.z));
        r[7] = __fadd_rn(r[7], __fmul_rn(u1.w, u1.w));
    }
    float s01 = __fadd_rn(r[0], r[1]);
    float s23 = __fadd_rn(r[2], r[3]);
    float s45 = __fadd_rn(r[4], r[5]);
    float s67 = __fadd_rn(r[6], r[7]);
    return __fadd_rn(__fadd_rn(s01, s23), __fadd_rn(s45, s67));
}
__device__ __forceinline__ float rownorm512(const float* __restrict__ row) {
    float b0 = pw128_sq(row);
    float b1 = pw128_sq(row + 128);
    float b2 = pw128_sq(row + 256);
    float b3 = pw128_sq(row + 384);
    return __fadd_rn(__fadd_rn(b0, b1), __fadd_rn(b2, b3));
}

// ---------------- norms kernel (numpy-faithful f32) + optional zero of loss / cnt ----------------
// launched with 64-thread blocks for grid spread (512 blocks for N=32768).
__global__ void k_norms(const float* __restrict__ a, float* __restrict__ out, int nrows,
                        float* __restrict__ loss_ptr, unsigned* __restrict__ cnt) {
    int r = blockIdx.x * blockDim.x + threadIdx.x;
    if (r == 0 && loss_ptr) *loss_ptr = 0.0f;
    if (r >= nrows) return;
    if (cnt) cnt[r] = 0u;
    out[r] = rownorm512(a + (size_t)r * D_DIM);
}

// ---------------- f32 -> bf16 (RNE) convert, 8 elems/thread ----------------
__global__ void k_cvt_bf16(const float* __restrict__ src, unsigned short* __restrict__ dst,
                           size_t n8) {
    size_t i = blockIdx.x * (size_t)blockDim.x + threadIdx.x;
    if (i >= n8) return;
    const float4* s = (const float4*)(src + i * 8);
    float4 v0 = s[0], v1 = s[1];
    float vv[8] = {v0.x, v0.y, v0.z, v0.w, v1.x, v1.y, v1.z, v1.w};
    unsigned u[8];
    #pragma unroll
    for (int j = 0; j < 8; ++j) {
        unsigned b = __float_as_uint(vv[j]);
        b = b + 0x7FFFu + ((b >> 16) & 1u);
        u[j] = b >> 16;
    }
    uint4 w;
    w.x = u[0] | (u[1] << 16);
    w.y = u[2] | (u[3] << 16);
    w.z = u[4] | (u[5] << 16);
    w.w = u[6] | (u[7] << 16);
    *(uint4*)(dst + i * 8) = w;
}

// ---------------- MFMA filter sweep (R1 structure: verified 488us) ----------------
// grid (128 Mtiles, 2 N-halves), 512 threads (8 waves as 4m x 2n, wave-tile 64x128).
// Block tile: 256 rows x 256 codes per nt step, BK=64, double-buffered LDS filled by
// global_load_lds (linear dest, inverse-XOR-swizzled source; XOR-swizzled ds_read).
// Running per-row min in LDS, candidate emission s' <= m + THETA (safe superset of all
// possible grid-argmin winners).
#define THETA 4.0e-4f

__global__ __launch_bounds__(512, 2)
void k_score(const unsigned short* __restrict__ Abf, const unsigned short* __restrict__ Bbf,
             const float* __restrict__ s2, unsigned* __restrict__ cnt,
             unsigned* __restrict__ cand, int N, int K) {
    // [buf][A=0/B=1][256 rows][64 k-elems], 128 KiB. Granule g (16B) of row r holds
    // k-slot (g ^ (r&7)) -> stride-128B rows read conflict-free (<=2-way).
    __shared__ unsigned short lds[2][2][256][64];
    __shared__ int minb[256];

    const int tid  = threadIdx.x;
    const int lane = tid & 63;
    const int wid  = tid >> 6;            // 0..7
    const int wm   = (wid >> 1) * 64;     // 0,64,128,192
    const int wn   = (wid & 1) * 128;     // 0,128
    const int col  = lane & 15;
    const int q8   = lane >> 4;           // 0..3
    const int xg   = col & 7;             // == row&7 for every fragment row we read
    const int m0   = blockIdx.x * 256;
    const int nhalf = K >> 1;             // 4096
    const int nb0  = blockIdx.y * nhalf;
    const int NT   = nhalf >> 8;          // 16 code tiles of 256
    const int G    = NT * 8;              // total BK=64 chunks in the sweep

    if (tid < 256) minb[tid] = 0x7F800000;  // +inf (positive-float-as-int ordering)

    // Staging geometry: thread covers LDS bytes {tid*16 + i*8192}, i=0..3 per operand.
    //   row r = srow + i*64, granule = tid&7, so source k-slot = (tid&7) ^ (srow&7)
    //   (i*64 == 0 mod 8 keeps the slot i-invariant).
    const int srow  = tid >> 3;                    // 0..63
    const int sslot = (tid & 7) ^ (srow & 7);      // inverse swizzle on the SOURCE side
    const unsigned short* aSrc0 = Abf + (size_t)(m0  + srow) * D_DIM + sslot * 8;
    const unsigned short* bSrc0 = Bbf + (size_t)(nb0 + srow) * D_DIM + sslot * 8;
    char* const ldsA0 = (char*)&lds[0][0][0][0] + tid * 16;
    char* const ldsB0 = (char*)&lds[0][1][0][0] + tid * 16;

    auto STAGE = [&](int gg) {
        const int b_  = gg & 1;
        const int kc_ = (gg & 7) << 6;             // k offset, 0..448
        const int nt_ = gg >> 3;                   // code tile
        const unsigned short* as_ = aSrc0 + kc_;
        const unsigned short* bs_ = bSrc0 + (size_t)nt_ * (256 * D_DIM) + kc_;
        char* ad = ldsA0 + b_ * 65536;
        char* bd = ldsB0 + b_ * 65536;
        #pragma unroll
        for (int i = 0; i < 4; ++i) {
            gload_lds16(as_ + (size_t)i * (64 * D_DIM), ad + i * 8192);
            gload_lds16(bs_ + (size_t)i * (64 * D_DIM), bd + i * 8192);
        }
    };

    STAGE(0);
    __syncthreads();   // compiler emits vmcnt(0) drain -> buf0 ready

    for (int nt = 0; nt < NT; ++nt) {
        // codebook norms for this tile straight into registers (L2-resident, hidden
        // under the chunk loop; only consumed in the epilogue)
        float s2r[8];
        #pragma unroll
        for (int nj = 0; nj < 8; ++nj)
            s2r[nj] = s2[nb0 + (nt << 8) + wn + nj * 16 + col];

        f32x4 acc[4][8];
        #pragma unroll
        for (int mi = 0; mi < 4; ++mi)
            #pragma unroll
            for (int nj = 0; nj < 8; ++nj) acc[mi][nj] = (f32x4){0.f, 0.f, 0.f, 0.f};

        #pragma unroll 2
        for (int t = 0; t < 8; ++t) {
            const int g = (nt << 3) + t;
            if (g + 1 < G) STAGE(g + 1);          // prefetch next chunk (other buffer)
            const int b = t & 1;                  // == g&1 (nt*8 is even)
            const char* baseA = (const char*)&lds[b][0][0][0];
            const char* baseB = (const char*)&lds[b][1][0][0];
            const int rowA = (wm + col) << 7;     // byte offset of this lane's A row
            const int rowB = (wn + col) << 7;
            #pragma unroll
            for (int ks = 0; ks < 2; ++ks) {
                const int gb = ((((ks << 2) | q8) ^ xg) << 4);   // swizzled granule byte
                bf16x8 af[4], bfr[8];
                #pragma unroll
                for (int mi = 0; mi < 4; ++mi)
                    af[mi] = *(const bf16x8*)(baseA + rowA + mi * 2048 + gb);
                #pragma unroll
                for (int nj = 0; nj < 8; ++nj)
                    bfr[nj] = *(const bf16x8*)(baseB + rowB + nj * 2048 + gb);
                #pragma unroll
                for (int mi = 0; mi < 4; ++mi)
                    #pragma unroll
                    for (int nj = 0; nj < 8; ++nj)
                        acc[mi][nj] = __builtin_amdgcn_mfma_f32_16x16x32_bf16(
                            af[mi], bfr[nj], acc[mi][nj], 0, 0, 0);
            }
            __syncthreads();   // lgkm drain for ds_reads + vmcnt drain for the prefetch
        }

        // pass 1: settle per-row tile min into minb; keep this wave's per-row tile min
        // in registers for pass-2 pruning.
        float vt[4][4];
        #pragma unroll
        for (int mi = 0; mi < 4; ++mi) {
            #pragma unroll
            for (int rg = 0; rg < 4; ++rg) {
                float v = 3e38f;
                #pragma unroll
                for (int nj = 0; nj < 8; ++nj) {
                    float sc = 0.5f + fmaf(-2.0f, acc[mi][nj][rg], s2r[nj]);
                    v = fminf(v, sc);
                }
                #pragma unroll
                for (int off = 1; off < 16; off <<= 1)
                    v = fminf(v, __shfl_xor(v, off, 64));
                vt[mi][rg] = v;
                if (col == 0)
                    atomicMin(&minb[wm + mi * 16 + q8 * 4 + rg], __float_as_int(v));
            }
        }
        __syncthreads();

        // pass 2: emit candidates within THETA of running min. Whole (mi,rg) groups are
        // skipped when this wave's tile-min can't reach the band (common case).
        const int cbase = nb0 + (nt << 8) + wn;
        #pragma unroll
        for (int mi = 0; mi < 4; ++mi) {
            #pragma unroll
            for (int rg = 0; rg < 4; ++rg) {
                const int rl = wm + mi * 16 + q8 * 4 + rg;
                const float m = __int_as_float(minb[rl]);
                if (vt[mi][rg] > m + THETA) continue;
                #pragma unroll
                for (int nj = 0; nj < 8; ++nj) {
                    float sc = 0.5f + fmaf(-2.0f, acc[mi][nj][rg], s2r[nj]);
                    if (sc <= m + THETA) {
                        const int grow = m0 + rl;
                        unsigned p = atomicAdd(&cnt[grow], 1u);
                        if (p < 32u) cand[(size_t)grow * 32 + p] = (unsigned)(cbase + nj * 16 + col);
                    }
                }
            }
        }
        // no trailing barrier needed: minb is monotone (emission stays a superset of
        // any-winner set) and the next chunk's barriers re-sync before minb is touched.
    }
}

// ---------------- refine: exact f64 dot + numpy-grid f32 score over candidates ----------------
// TLP fix: 2 rows per wave. Grid N/8 blocks of 4 waves -> 16k waves, 0 LDS, low VGPR
// -> many blocks/CU resident; per-candidate latency chain hidden by wave multiplexing.
__global__ __launch_bounds__(256)
void k_refine(const float* __restrict__ x, const float* __restrict__ emb,
              const float* __restrict__ s1, const float* __restrict__ s2,
              const unsigned* __restrict__ cnt, const unsigned* __restrict__ cand,
              float* __restrict__ idx_out, int N, int K) {
    const int lane = threadIdx.x & 63;
    const int wgid = blockIdx.x * 4 + (threadIdx.x >> 6);
    const int row0 = wgid * 2;
    for (int rr = 0; rr < 2; ++rr) {
        int row = row0 + rr;
        if (row >= N) return;
        const float* xr = x + (size_t)row * D_DIM;
        float4 xa = *(const float4*)(xr + lane * 8);
        float4 xb = *(const float4*)(xr + lane * 8 + 4);
        unsigned c = cnt[row];
        float s1r = s1[row];
        float bs = 3e38f;
        int bi = 0;
        bool have = false;
        if (c >= 1u && c <= 32u) {
            for (unsigned i = 0; i < c; ++i) {
                int code = (int)cand[(size_t)row * 32 + i];
                const float* er = emb + (size_t)code * D_DIM;
                float4 ea = *(const float4*)(er + lane * 8);
                float4 eb = *(const float4*)(er + lane * 8 + 4);
                double d = 0.0;
                d = fma((double)xa.x, (double)ea.x, d);
                d = fma((double)xa.y, (double)ea.y, d);
                d = fma((double)xa.z, (double)ea.z, d);
                d = fma((double)xa.w, (double)ea.w, d);
                d = fma((double)xb.x, (double)eb.x, d);
                d = fma((double)xb.y, (double)eb.y, d);
                d = fma((double)xb.z, (double)eb.z, d);
                d = fma((double)xb.w, (double)eb.w, d);
                #pragma unroll
                for (int off = 32; off > 0; off >>= 1) d += __shfl_down(d, off, 64);
                if (lane == 0) {
                    float tt = __fadd_rn(s1r, s2[code]);
                    float u  = __fmul_rn(2.0f, (float)d);
                    float s  = __fadd_rn(tt, -u);
                    if (!have || s < bs || (s == bs && code < bi)) { bs = s; bi = code; have = true; }
                }
            }
        } else {
            // overflow (or impossible zero) -> exact full scan
            for (int code = 0; code < K; ++code) {
                const float* er = emb + (size_t)code * D_DIM;
                float4 ea = *(const float4*)(er + lane * 8);
                float4 eb = *(const float4*)(er + lane * 8 + 4);
                double d = 0.0;
                d = fma((double)xa.x, (double)ea.x, d);
                d = fma((double)xa.y, (double)ea.y, d);
                d = fma((double)xa.z, (double)ea.z, d);
                d = fma((double)xa.w, (double)ea.w, d);
                d = fma((double)xb.x, (double)eb.x, d);
                d = fma((double)xb.y, (double)eb.y, d);
                d = fma((double)xb.z, (double)eb.z, d);
                d = fma((double)xb.w, (double)eb.w, d);
                #pragma unroll
                for (int off = 32; off > 0; off >>= 1) d += __shfl_down(d, off, 64);
                if (lane == 0) {
                    float tt = __fadd_rn(s1r, s2[code]);
                    float u  = __fmul_rn(2.0f, (float)d);
                    float s  = __fadd_rn(tt, -u);
                    if (!have || s < bs) { bs = s; bi = code; have = true; }
                }
            }
        }
        if (lane == 0) idx_out[row] = (float)bi;
    }
}

// ---------------- fallback: R3's passing f64 argmin (used if ws too small) ----------------
constexpr int BM = 64;
constexpr int BN = 128;
constexpr int BD = 32;
constexpr int TX = 16;
struct TileView { float xs[BD][BM + 4]; float es[BD][BN + 4]; };
struct RedView  { float s[BM][TX + 1]; int i[BM][TX + 1]; };

__global__ __launch_bounds__(256)
void k_argmin(const float* __restrict__ x, const float* __restrict__ emb,
              const float* __restrict__ s1, const float* __restrict__ s2,
              float* __restrict__ idx_out, int N, int K) {
    __shared__ alignas(16) char smem_raw[sizeof(TileView) > sizeof(RedView)
                                         ? sizeof(TileView) : sizeof(RedView)];
    TileView& t = *reinterpret_cast<TileView*>(smem_raw);
    RedView&  r = *reinterpret_cast<RedView*>(smem_raw);
    __shared__ float ces[BN];
    const int tid = threadIdx.x;
    const int tx = tid & 15;
    const int ty = tid >> 4;
    const int rowBase = blockIdx.x * BM;
    if (rowBase >= N) return;
    float rs1[4];
    #pragma unroll
    for (int i = 0; i < 4; ++i) rs1[i] = s1[rowBase + 4 * ty + i];
    float bs[4] = {3.0e38f, 3.0e38f, 3.0e38f, 3.0e38f};
    int   bi[4] = {0, 0, 0, 0};
    for (int nt = 0; nt < K; nt += BN) {
        double acc[4][8];
        #pragma unroll
        for (int i = 0; i < 4; ++i)
            #pragma unroll
            for (int j = 0; j < 8; ++j) acc[i][j] = 0.0;
        for (int dc = 0; dc < D_DIM; dc += BD) {
            __syncthreads();
            #pragma unroll
            for (int i = 0; i < 2; ++i) {
                int q = tid + i * 256;
                int rr = q >> 3, c4 = q & 7;
                float4 v = *(const float4*)(x + (size_t)(rowBase + rr) * D_DIM + dc + 4 * c4);
                t.xs[4 * c4 + 0][rr] = v.x; t.xs[4 * c4 + 1][rr] = v.y;
                t.xs[4 * c4 + 2][rr] = v.z; t.xs[4 * c4 + 3][rr] = v.w;
            }
            #pragma unroll
            for (int i = 0; i < 4; ++i) {
                int q = tid + i * 256;
                int rr = q >> 3, c4 = q & 7;
                float4 v = *(const float4*)(emb + (size_t)(nt + rr) * D_DIM + dc + 4 * c4);
                t.es[4 * c4 + 0][rr] = v.x; t.es[4 * c4 + 1][rr] = v.y;
                t.es[4 * c4 + 2][rr] = v.z; t.es[4 * c4 + 3][rr] = v.w;
            }
            if (dc == 0 && tid < BN) ces[tid] = s2[nt + tid];
            __syncthreads();
            #pragma unroll
            for (int d = 0; d < BD; ++d) {
                float4 af = *(const float4*)&t.xs[d][4 * ty];
                float4 b0 = *(const float4*)&t.es[d][4 * tx];
                float4 b1 = *(const float4*)&t.es[d][64 + 4 * tx];
                double a[4] = {af.x, af.y, af.z, af.w};
                double b[8] = {b0.x, b0.y, b0.z, b0.w, b1.x, b1.y, b1.z, b1.w};
                #pragma unroll
                for (int i = 0; i < 4; ++i)
                    #pragma unroll
                    for (int j = 0; j < 8; ++j)
                        acc[i][j] = fma(a[i], b[j], acc[i][j]);
            }
        }
        #pragma unroll
        for (int j = 0; j < 8; ++j) {
            int cc = (j < 4) ? (4 * tx + j) : (64 + 4 * tx + (j - 4));
            int code = nt + cc;
            float ce = ces[cc];
            #pragma unroll
            for (int i = 0; i < 4; ++i) {
                float tt = __fadd_rn(rs1[i], ce);
                float u  = __fmul_rn(2.0f, (float)acc[i][j]);
                float s  = __fadd_rn(tt, -u);
                if (s < bs[i]) { bs[i] = s; bi[i] = code; }
            }
        }
    }
    __syncthreads();
    #pragma unroll
    for (int i = 0; i < 4; ++i) { r.s[4 * ty + i][tx] = bs[i]; r.i[4 * ty + i][tx] = bi[i]; }
    __syncthreads();
    if (tid < BM) {
        float best = r.s[tid][0];
        int bidx = r.i[tid][0];
        #pragma unroll
        for (int tt = 1; tt < TX; ++tt) {
            float s = r.s[tid][tt];
            int ii = r.i[tid][tt];
            if (s < best || (s == best && ii < bidx)) { best = s; bidx = ii; }
        }
        idx_out[rowBase + tid] = (float)bidx;
    }
}

// ---------------- gather + straight-through output + loss ----------------
// 16 rows per 256-thread block (grid N/16): coalesced float4 passes, per-thread loss
// accumulation, ONE atomicAdd per block (16x fewer contended atomics than 1-row/block).
__global__ __launch_bounds__(256)
void k_gather(const float* __restrict__ x, const float* __restrict__ emb,
              const float* __restrict__ idx_f, float* __restrict__ out,
              float* __restrict__ loss_ptr, float loss_scale, int N) {
    const int t   = threadIdx.x;
    const int r0  = blockIdx.x * 16;
    const int sub = t >> 7;              // 0..1 (row within a pass)
    const int col = (t & 127) * 4;       // 128 threads x 4 floats = 512 cols
    float lsum = 0.0f;
    #pragma unroll
    for (int p = 0; p < 8; ++p) {
        const int row = r0 + p * 2 + sub;
        if (row >= N) break;
        const int idx = (int)idx_f[row];
        const float4 xv = *(const float4*)(x + (size_t)row * D_DIM + col);
        const float4 ev = *(const float4*)(emb + (size_t)idx * D_DIM + col);
        float4 o;
        o.x = xv.x * 0.95f + (ev.x - xv.x) * 0.05f;
        o.y = xv.y * 0.95f + (ev.y - xv.y) * 0.05f;
        o.z = xv.z * 0.95f + (ev.z - xv.z) * 0.05f;
        o.w = xv.w * 0.95f + (ev.w - xv.w) * 0.05f;
        *(float4*)(out + (size_t)row * D_DIM + col) = o;
        float d0 = ev.x - xv.x, d1 = ev.y - xv.y, d2 = ev.z - xv.z, d3 = ev.w - xv.w;
        lsum += d0 * d0 + d1 * d1 + d2 * d2 + d3 * d3;
    }
    #pragma unroll
    for (int off = 32; off > 0; off >>= 1) lsum += __shfl_down(lsum, off, 64);
    __shared__ float wsum[4];
    if ((t & 63) == 0) wsum[t >> 6] = lsum;
    __syncthreads();
    if (t == 0)
        atomicAdd(loss_ptr, (wsum[0] + wsum[1] + wsum[2] + wsum[3]) * loss_scale);
}

extern "C" void kernel_launch(void* const* d_in, const int* in_sizes, int n_in,
                              void* d_out, int out_size, void* d_ws, size_t ws_size,
                              hipStream_t stream) {
    const float* x   = (const float*)d_in[0];
    const float* emb = (const float*)d_in[1];
    const int N = in_sizes[0] / D_DIM;   // 32768
    const int K = in_sizes[1] / D_DIM;   // 8192

    float* out      = (float*)d_out;
    float* idx_out  = out + (size_t)N * D_DIM;
    float* loss_ptr = idx_out + N;

    char* ws = (char*)d_ws;
    size_t offA    = 0;
    size_t offB    = offA + (size_t)N * D_DIM * 2;
    size_t offS2   = offB + (size_t)K * D_DIM * 2;
    size_t offS1   = offS2 + (size_t)K * 4;
    size_t offCnt  = offS1 + (size_t)N * 4;
    size_t offCand = offCnt + (size_t)N * 4;
    size_t need    = offCand + (size_t)N * 32 * 4;

    const float loss_scale = 1.25f / ((float)N * (float)D_DIM);

    bool fast = (ws_size >= need) && (N % 256 == 0) && (K % 512 == 0);
    if (fast) {
        unsigned short* A = (unsigned short*)(ws + offA);
        unsigned short* B = (unsigned short*)(ws + offB);
        float* s2    = (float*)(ws + offS2);
        float* s1    = (float*)(ws + offS1);
        unsigned* cnt  = (unsigned*)(ws + offCnt);
        unsigned* cand = (unsigned*)(ws + offCand);

        k_norms<<<(K + 63) / 64, 64, 0, stream>>>(emb, s2, K, loss_ptr, nullptr);
        k_norms<<<(N + 63) / 64, 64, 0, stream>>>(x, s1, N, nullptr, cnt);
        k_cvt_bf16<<<(N * (D_DIM / 8)) / 256, 256, 0, stream>>>(x, A, (size_t)N * (D_DIM / 8));
        k_cvt_bf16<<<(K * (D_DIM / 8)) / 256, 256, 0, stream>>>(emb, B, (size_t)K * (D_DIM / 8));
        k_score<<<dim3(N / 256, 2), 512, 0, stream>>>(A, B, s2, cnt, cand, N, K);
        k_refine<<<N / 8, 256, 0, stream>>>(x, emb, s1, s2, cnt, cand, idx_out, N, K);
    } else {
        float* s2 = (float*)d_ws;
        float* s1 = s2 + K;
        k_norms<<<(K + 63) / 64, 64, 0, stream>>>(emb, s2, K, loss_ptr, nullptr);
        k_norms<<<(N + 63) / 64, 64, 0, stream>>>(x, s1, N, nullptr, nullptr);
        k_argmin<<<N / BM, 256, 0, stream>>>(x, emb, s1, s2, idx_out, N, K);
    }
    k_gather<<<(N + 15) / 16, 256, 0, stream>>>(x, emb, idx_out, out, loss_ptr, loss_scale, N);
}

// Round 7
// 685.162 us; speedup vs baseline: 26.7047x; 1.1012x over previous
//
#include <hip/hip_runtime.h>
#include <math.h>

#define D_DIM 512

typedef __attribute__((ext_vector_type(8))) short bf16x8;
typedef __attribute__((ext_vector_type(4))) float f32x4;

#define AS1 __attribute__((address_space(1)))
#define AS3 __attribute__((address_space(3)))

// async global->LDS, 16B per lane. LDS dest must be wave-uniform base + lane*16.
__device__ __forceinline__ void gload_lds16(const void* g, void* l) {
    __builtin_amdgcn_global_load_lds((AS1 const void*)g, (AS3 void*)l, 16, 0, 0);
}

// ---------- numpy pairwise-sum replica for sum(v*v) over 512 contiguous floats ----------
// float4-vectorized; the __fmul_rn/__fadd_rn op sequence (8 accumulators, pairwise tail)
// is IDENTICAL to the scalar version -> bit-exact same result, 4x fewer load instrs.
__device__ __forceinline__ float pw128_sq(const float* __restrict__ a) {
    float4 v0 = *(const float4*)(a);
    float4 v1 = *(const float4*)(a + 4);
    float r[8];
    r[0] = __fmul_rn(v0.x, v0.x); r[1] = __fmul_rn(v0.y, v0.y);
    r[2] = __fmul_rn(v0.z, v0.z); r[3] = __fmul_rn(v0.w, v0.w);
    r[4] = __fmul_rn(v1.x, v1.x); r[5] = __fmul_rn(v1.y, v1.y);
    r[6] = __fmul_rn(v1.z, v1.z); r[7] = __fmul_rn(v1.w, v1.w);
    #pragma unroll
    for (int i = 8; i < 128; i += 8) {
        float4 u0 = *(const float4*)(a + i);
        float4 u1 = *(const float4*)(a + i + 4);
        r[0] = __fadd_rn(r[0], __fmul_rn(u0.x, u0.x));
        r[1] = __fadd_rn(r[1], __fmul_rn(u0.y, u0.y));
        r[2] = __fadd_rn(r[2], __fmul_rn(u0.z, u0.z));
        r[3] = __fadd_rn(r[3], __fmul_rn(u0.w, u0.w));
        r[4] = __fadd_rn(r[4], __fmul_rn(u1.x, u1.x));
        r[5] = __fadd_rn(r[5], __fmul_rn(u1.y, u1.y));
        r[6] = __fadd_rn(r[6], __fmul_rn(u1.z, u1.z));
        r[7] = __fadd_rn(r[7], __fmul_rn(u1.w, u1.w));
    }
    float s01 = __fadd_rn(r[0], r[1]);
    float s23 = __fadd_rn(r[2], r[3]);
    float s45 = __fadd_rn(r[4], r[5]);
    float s67 = __fadd_rn(r[6], r[7]);
    return __fadd_rn(__fadd_rn(s01, s23), __fadd_rn(s45, s67));
}
__device__ __forceinline__ float rownorm512(const float* __restrict__ row) {
    float b0 = pw128_sq(row);
    float b1 = pw128_sq(row + 128);
    float b2 = pw128_sq(row + 256);
    float b3 = pw128_sq(row + 384);
    return __fadd_rn(__fadd_rn(b0, b1), __fadd_rn(b2, b3));
}

// ---------------- norms kernel (numpy-faithful f32) + optional zero of loss / cnt ----------------
// launched with 64-thread blocks for grid spread (512 blocks for N=32768).
__global__ void k_norms(const float* __restrict__ a, float* __restrict__ out, int nrows,
                        float* __restrict__ loss_ptr, unsigned* __restrict__ cnt) {
    int r = blockIdx.x * blockDim.x + threadIdx.x;
    if (r == 0 && loss_ptr) *loss_ptr = 0.0f;
    if (r >= nrows) return;
    if (cnt) cnt[r] = 0u;
    out[r] = rownorm512(a + (size_t)r * D_DIM);
}

// ---------------- f32 -> bf16 (RNE) convert, 8 elems/thread ----------------
__global__ void k_cvt_bf16(const float* __restrict__ src, unsigned short* __restrict__ dst,
                           size_t n8) {
    size_t i = blockIdx.x * (size_t)blockDim.x + threadIdx.x;
    if (i >= n8) return;
    const float4* s = (const float4*)(src + i * 8);
    float4 v0 = s[0], v1 = s[1];
    float vv[8] = {v0.x, v0.y, v0.z, v0.w, v1.x, v1.y, v1.z, v1.w};
    unsigned u[8];
    #pragma unroll
    for (int j = 0; j < 8; ++j) {
        unsigned b = __float_as_uint(vv[j]);
        b = b + 0x7FFFu + ((b >> 16) & 1u);
        u[j] = b >> 16;
    }
    uint4 w;
    w.x = u[0] | (u[1] << 16);
    w.y = u[2] | (u[3] << 16);
    w.z = u[4] | (u[5] << 16);
    w.w = u[6] | (u[7] << 16);
    *(uint4*)(dst + i * 8) = w;
}

// ---------------- MFMA filter sweep (v7: 128x256 tile, BK=32, 2 blocks/CU) ----------------
// grid (N/128=256 Mtiles, 2 N-halves) = 512 blocks -> 2 co-resident blocks/CU (the m114
// inter-block overlap mechanism that hides per-chunk barrier drains). 512 threads =
// 8 waves as 2M x 4N (wave-tile 64x64, acc[4][4]). LDS 48KiB dbuf, launch_bounds(512,4)
// caps VGPR at 128 so 2 blocks actually fit. Emission statistics identical to R1/R6:
// each row sees exactly 2 half-sweeps with 256-code tiles.
// Swizzle for 64B rows (4x16B granules): physical granule p = (g + (row>>1)) & 3.
// Read buckets (row&1, p) put 8 lanes on each 4-bank group -> conflict-free; staging
// applies the inverse rotation on the global source address (LDS dest stays linear).
// Per-acc K-accumulation order: ascending k in 32-steps -> bit-identical scores.
#define THETA 4.0e-4f

__global__ __launch_bounds__(512, 4)
void k_score(const unsigned short* __restrict__ Abf, const unsigned short* __restrict__ Bbf,
             const float* __restrict__ s2, unsigned* __restrict__ cnt,
             unsigned* __restrict__ cand, int N, int K) {
    __shared__ unsigned short ldsA[2][128][32];   // 16 KiB
    __shared__ unsigned short ldsB[2][256][32];   // 32 KiB
    __shared__ int minb[128];

    const int tid  = threadIdx.x;
    const int lane = tid & 63;
    const int wid  = tid >> 6;            // 0..7
    const int wm   = (wid >> 2) * 64;     // 0,64   (2 M-waves)
    const int wn   = (wid & 3) * 64;      // 0,64,128,192 (4 N-waves)
    const int col  = lane & 15;
    const int q8   = lane >> 4;           // 0..3 (logical 16B granule of the 64B row)
    const int m0   = blockIdx.x * 128;
    const int nhalf = K >> 1;             // 4096
    const int nb0  = blockIdx.y * nhalf;
    const int NT   = nhalf >> 8;          // 16 code tiles of 256
    const int G    = NT * 16;             // total BK=32 chunks in the sweep

    if (tid < 128) minb[tid] = 0x7F800000;  // +inf (positive-float-as-int ordering)

    // Staging: thread covers LDS bytes tid*16 (A) and tid*16 (+8192) (B).
    //   A: row = tid>>2 (0..127), phys slot = tid&3.
    //   B: rows tid>>2 and tid>>2+128 -> (row>>1)&3 identical for both parts.
    //   logical granule g = (p - (row>>1)) & 3  (inverse of p = (g + row>>1) & 3).
    const int srow = tid >> 2;
    const int sg   = ((tid & 3) + 4 - ((tid >> 3) & 3)) & 3;

    auto STAGE = [&](int gg) {
        const int b_  = gg & 1;
        const int kc_ = (gg & 15) << 5;            // k offset (elements), 0..480
        const int nt_ = gg >> 4;                   // code tile
        const unsigned short* as_ = Abf + (size_t)(m0 + srow) * D_DIM + kc_ + sg * 8;
        const unsigned short* bs_ = Bbf + (size_t)(nb0 + nt_ * 256 + srow) * D_DIM + kc_ + sg * 8;
        gload_lds16(as_, (char*)&ldsA[b_][0][0] + tid * 16);
        gload_lds16(bs_, (char*)&ldsB[b_][0][0] + tid * 16);
        gload_lds16(bs_ + (size_t)128 * D_DIM, (char*)&ldsB[b_][0][0] + tid * 16 + 8192);
    };

    STAGE(0);
    __syncthreads();   // buf0 ready

    for (int nt = 0; nt < NT; ++nt) {
        // codebook norms for this tile straight into registers (consumed in epilogue)
        float s2r[4];
        #pragma unroll
        for (int nj = 0; nj < 4; ++nj)
            s2r[nj] = s2[nb0 + (nt << 8) + wn + nj * 16 + col];

        f32x4 acc[4][4];
        #pragma unroll
        for (int mi = 0; mi < 4; ++mi)
            #pragma unroll
            for (int nj = 0; nj < 4; ++nj) acc[mi][nj] = (f32x4){0.f, 0.f, 0.f, 0.f};

        #pragma unroll 2
        for (int t = 0; t < 16; ++t) {
            const int g = (nt << 4) + t;
            if (g + 1 < G) STAGE(g + 1);          // prefetch next chunk (other buffer)
            const int b = t & 1;                  // == g&1 (nt*16 is even)
            bf16x8 af[4], bfr[4];
            #pragma unroll
            for (int mi = 0; mi < 4; ++mi) {
                const int R = wm + mi * 16 + col;
                const int p = (q8 + (R >> 1)) & 3;
                af[mi] = *(const bf16x8*)((const char*)&ldsA[b][0][0] + R * 64 + p * 16);
            }
            #pragma unroll
            for (int nj = 0; nj < 4; ++nj) {
                const int R = wn + nj * 16 + col;
                const int p = (q8 + (R >> 1)) & 3;
                bfr[nj] = *(const bf16x8*)((const char*)&ldsB[b][0][0] + R * 64 + p * 16);
            }
            #pragma unroll
            for (int mi = 0; mi < 4; ++mi)
                #pragma unroll
                for (int nj = 0; nj < 4; ++nj)
                    acc[mi][nj] = __builtin_amdgcn_mfma_f32_16x16x32_bf16(
                        af[mi], bfr[nj], acc[mi][nj], 0, 0, 0);
            __syncthreads();   // drain prefetch + all reads of buf b done
        }

        // pass 1: settle per-row tile min into minb; keep this wave's per-row tile min
        // in registers for pass-2 pruning.
        float vt[4][4];
        #pragma unroll
        for (int mi = 0; mi < 4; ++mi) {
            #pragma unroll
            for (int rg = 0; rg < 4; ++rg) {
                float v = 3e38f;
                #pragma unroll
                for (int nj = 0; nj < 4; ++nj) {
                    float sc = 0.5f + fmaf(-2.0f, acc[mi][nj][rg], s2r[nj]);
                    v = fminf(v, sc);
                }
                #pragma unroll
                for (int off = 1; off < 16; off <<= 1)
                    v = fminf(v, __shfl_xor(v, off, 64));
                vt[mi][rg] = v;
                if (col == 0)
                    atomicMin(&minb[wm + mi * 16 + q8 * 4 + rg], __float_as_int(v));
            }
        }
        __syncthreads();

        // pass 2: emit candidates within THETA of running min. Whole (mi,rg) groups are
        // skipped when this wave's tile-min can't reach the band (common case).
        const int cbase = nb0 + (nt << 8) + wn;
        #pragma unroll
        for (int mi = 0; mi < 4; ++mi) {
            #pragma unroll
            for (int rg = 0; rg < 4; ++rg) {
                const int rl = wm + mi * 16 + q8 * 4 + rg;
                const float m = __int_as_float(minb[rl]);
                if (vt[mi][rg] > m + THETA) continue;
                #pragma unroll
                for (int nj = 0; nj < 4; ++nj) {
                    float sc = 0.5f + fmaf(-2.0f, acc[mi][nj][rg], s2r[nj]);
                    if (sc <= m + THETA) {
                        const int grow = m0 + rl;
                        unsigned p = atomicAdd(&cnt[grow], 1u);
                        if (p < 32u) cand[(size_t)grow * 32 + p] = (unsigned)(cbase + nj * 16 + col);
                    }
                }
            }
        }
        // no trailing barrier needed: minb is monotone (emission stays a superset of
        // any-winner set) and the next chunk's barriers re-sync before minb is touched.
    }
}

// ---------------- refine: exact f64 dot + numpy-grid f32 score over candidates ----------------
// TLP fix: 2 rows per wave. Grid N/8 blocks of 4 waves -> 16k waves, 0 LDS, low VGPR
// -> many blocks/CU resident; per-candidate latency chain hidden by wave multiplexing.
__global__ __launch_bounds__(256)
void k_refine(const float* __restrict__ x, const float* __restrict__ emb,
              const float* __restrict__ s1, const float* __restrict__ s2,
              const unsigned* __restrict__ cnt, const unsigned* __restrict__ cand,
              float* __restrict__ idx_out, int N, int K) {
    const int lane = threadIdx.x & 63;
    const int wgid = blockIdx.x * 4 + (threadIdx.x >> 6);
    const int row0 = wgid * 2;
    for (int rr = 0; rr < 2; ++rr) {
        int row = row0 + rr;
        if (row >= N) return;
        const float* xr = x + (size_t)row * D_DIM;
        float4 xa = *(const float4*)(xr + lane * 8);
        float4 xb = *(const float4*)(xr + lane * 8 + 4);
        unsigned c = cnt[row];
        float s1r = s1[row];
        float bs = 3e38f;
        int bi = 0;
        bool have = false;
        if (c >= 1u && c <= 32u) {
            for (unsigned i = 0; i < c; ++i) {
                int code = (int)cand[(size_t)row * 32 + i];
                const float* er = emb + (size_t)code * D_DIM;
                float4 ea = *(const float4*)(er + lane * 8);
                float4 eb = *(const float4*)(er + lane * 8 + 4);
                double d = 0.0;
                d = fma((double)xa.x, (double)ea.x, d);
                d = fma((double)xa.y, (double)ea.y, d);
                d = fma((double)xa.z, (double)ea.z, d);
                d = fma((double)xa.w, (double)ea.w, d);
                d = fma((double)xb.x, (double)eb.x, d);
                d = fma((double)xb.y, (double)eb.y, d);
                d = fma((double)xb.z, (double)eb.z, d);
                d = fma((double)xb.w, (double)eb.w, d);
                #pragma unroll
                for (int off = 32; off > 0; off >>= 1) d += __shfl_down(d, off, 64);
                if (lane == 0) {
                    float tt = __fadd_rn(s1r, s2[code]);
                    float u  = __fmul_rn(2.0f, (float)d);
                    float s  = __fadd_rn(tt, -u);
                    if (!have || s < bs || (s == bs && code < bi)) { bs = s; bi = code; have = true; }
                }
            }
        } else {
            // overflow (or impossible zero) -> exact full scan
            for (int code = 0; code < K; ++code) {
                const float* er = emb + (size_t)code * D_DIM;
                float4 ea = *(const float4*)(er + lane * 8);
                float4 eb = *(const float4*)(er + lane * 8 + 4);
                double d = 0.0;
                d = fma((double)xa.x, (double)ea.x, d);
                d = fma((double)xa.y, (double)ea.y, d);
                d = fma((double)xa.z, (double)ea.z, d);
                d = fma((double)xa.w, (double)ea.w, d);
                d = fma((double)xb.x, (double)eb.x, d);
                d = fma((double)xb.y, (double)eb.y, d);
                d = fma((double)xb.z, (double)eb.z, d);
                d = fma((double)xb.w, (double)eb.w, d);
                #pragma unroll
                for (int off = 32; off > 0; off >>= 1) d += __shfl_down(d, off, 64);
                if (lane == 0) {
                    float tt = __fadd_rn(s1r, s2[code]);
                    float u  = __fmul_rn(2.0f, (float)d);
                    float s  = __fadd_rn(tt, -u);
                    if (!have || s < bs) { bs = s; bi = code; have = true; }
                }
            }
        }
        if (lane == 0) idx_out[row] = (float)bi;
    }
}

// ---------------- fallback: R3's passing f64 argmin (used if ws too small) ----------------
constexpr int BM = 64;
constexpr int BN = 128;
constexpr int BD = 32;
constexpr int TX = 16;
struct TileView { float xs[BD][BM + 4]; float es[BD][BN + 4]; };
struct RedView  { float s[BM][TX + 1]; int i[BM][TX + 1]; };

__global__ __launch_bounds__(256)
void k_argmin(const float* __restrict__ x, const float* __restrict__ emb,
              const float* __restrict__ s1, const float* __restrict__ s2,
              float* __restrict__ idx_out, int N, int K) {
    __shared__ alignas(16) char smem_raw[sizeof(TileView) > sizeof(RedView)
                                         ? sizeof(TileView) : sizeof(RedView)];
    TileView& t = *reinterpret_cast<TileView*>(smem_raw);
    RedView&  r = *reinterpret_cast<RedView*>(smem_raw);
    __shared__ float ces[BN];
    const int tid = threadIdx.x;
    const int tx = tid & 15;
    const int ty = tid >> 4;
    const int rowBase = blockIdx.x * BM;
    if (rowBase >= N) return;
    float rs1[4];
    #pragma unroll
    for (int i = 0; i < 4; ++i) rs1[i] = s1[rowBase + 4 * ty + i];
    float bs[4] = {3.0e38f, 3.0e38f, 3.0e38f, 3.0e38f};
    int   bi[4] = {0, 0, 0, 0};
    for (int nt = 0; nt < K; nt += BN) {
        double acc[4][8];
        #pragma unroll
        for (int i = 0; i < 4; ++i)
            #pragma unroll
            for (int j = 0; j < 8; ++j) acc[i][j] = 0.0;
        for (int dc = 0; dc < D_DIM; dc += BD) {
            __syncthreads();
            #pragma unroll
            for (int i = 0; i < 2; ++i) {
                int q = tid + i * 256;
                int rr = q >> 3, c4 = q & 7;
                float4 v = *(const float4*)(x + (size_t)(rowBase + rr) * D_DIM + dc + 4 * c4);
                t.xs[4 * c4 + 0][rr] = v.x; t.xs[4 * c4 + 1][rr] = v.y;
                t.xs[4 * c4 + 2][rr] = v.z; t.xs[4 * c4 + 3][rr] = v.w;
            }
            #pragma unroll
            for (int i = 0; i < 4; ++i) {
                int q = tid + i * 256;
                int rr = q >> 3, c4 = q & 7;
                float4 v = *(const float4*)(emb + (size_t)(nt + rr) * D_DIM + dc + 4 * c4);
                t.es[4 * c4 + 0][rr] = v.x; t.es[4 * c4 + 1][rr] = v.y;
                t.es[4 * c4 + 2][rr] = v.z; t.es[4 * c4 + 3][rr] = v.w;
            }
            if (dc == 0 && tid < BN) ces[tid] = s2[nt + tid];
            __syncthreads();
            #pragma unroll
            for (int d = 0; d < BD; ++d) {
                float4 af = *(const float4*)&t.xs[d][4 * ty];
                float4 b0 = *(const float4*)&t.es[d][4 * tx];
                float4 b1 = *(const float4*)&t.es[d][64 + 4 * tx];
                double a[4] = {af.x, af.y, af.z, af.w};
                double b[8] = {b0.x, b0.y, b0.z, b0.w, b1.x, b1.y, b1.z, b1.w};
                #pragma unroll
                for (int i = 0; i < 4; ++i)
                    #pragma unroll
                    for (int j = 0; j < 8; ++j)
                        acc[i][j] = fma(a[i], b[j], acc[i][j]);
            }
        }
        #pragma unroll
        for (int j = 0; j < 8; ++j) {
            int cc = (j < 4) ? (4 * tx + j) : (64 + 4 * tx + (j - 4));
            int code = nt + cc;
            float ce = ces[cc];
            #pragma unroll
            for (int i = 0; i < 4; ++i) {
                float tt = __fadd_rn(rs1[i], ce);
                float u  = __fmul_rn(2.0f, (float)acc[i][j]);
                float s  = __fadd_rn(tt, -u);
                if (s < bs[i]) { bs[i] = s; bi[i] = code; }
            }
        }
    }
    __syncthreads();
    #pragma unroll
    for (int i = 0; i < 4; ++i) { r.s[4 * ty + i][tx] = bs[i]; r.i[4 * ty + i][tx] = bi[i]; }
    __syncthreads();
    if (tid < BM) {
        float best = r.s[tid][0];
        int bidx = r.i[tid][0];
        #pragma unroll
        for (int tt = 1; tt < TX; ++tt) {
            float s = r.s[tid][tt];
            int ii = r.i[tid][tt];
            if (s < best || (s == best && ii < bidx)) { best = s; bidx = ii; }
        }
        idx_out[rowBase + tid] = (float)bidx;
    }
}

// ---------------- gather + straight-through output + loss ----------------
// 16 rows per 256-thread block (grid N/16): coalesced float4 passes, per-thread loss
// accumulation, ONE atomicAdd per block (16x fewer contended atomics than 1-row/block).
__global__ __launch_bounds__(256)
void k_gather(const float* __restrict__ x, const float* __restrict__ emb,
              const float* __restrict__ idx_f, float* __restrict__ out,
              float* __restrict__ loss_ptr, float loss_scale, int N) {
    const int t   = threadIdx.x;
    const int r0  = blockIdx.x * 16;
    const int sub = t >> 7;              // 0..1 (row within a pass)
    const int col = (t & 127) * 4;       // 128 threads x 4 floats = 512 cols
    float lsum = 0.0f;
    #pragma unroll
    for (int p = 0; p < 8; ++p) {
        const int row = r0 + p * 2 + sub;
        if (row >= N) break;
        const int idx = (int)idx_f[row];
        const float4 xv = *(const float4*)(x + (size_t)row * D_DIM + col);
        const float4 ev = *(const float4*)(emb + (size_t)idx * D_DIM + col);
        float4 o;
        o.x = xv.x * 0.95f + (ev.x - xv.x) * 0.05f;
        o.y = xv.y * 0.95f + (ev.y - xv.y) * 0.05f;
        o.z = xv.z * 0.95f + (ev.z - xv.z) * 0.05f;
        o.w = xv.w * 0.95f + (ev.w - xv.w) * 0.05f;
        *(float4*)(out + (size_t)row * D_DIM + col) = o;
        float d0 = ev.x - xv.x, d1 = ev.y - xv.y, d2 = ev.z - xv.z, d3 = ev.w - xv.w;
        lsum += d0 * d0 + d1 * d1 + d2 * d2 + d3 * d3;
    }
    #pragma unroll
    for (int off = 32; off > 0; off >>= 1) lsum += __shfl_down(lsum, off, 64);
    __shared__ float wsum[4];
    if ((t & 63) == 0) wsum[t >> 6] = lsum;
    __syncthreads();
    if (t == 0)
        atomicAdd(loss_ptr, (wsum[0] + wsum[1] + wsum[2] + wsum[3]) * loss_scale);
}

extern "C" void kernel_launch(void* const* d_in, const int* in_sizes, int n_in,
                              void* d_out, int out_size, void* d_ws, size_t ws_size,
                              hipStream_t stream) {
    const float* x   = (const float*)d_in[0];
    const float* emb = (const float*)d_in[1];
    const int N = in_sizes[0] / D_DIM;   // 32768
    const int K = in_sizes[1] / D_DIM;   // 8192

    float* out      = (float*)d_out;
    float* idx_out  = out + (size_t)N * D_DIM;
    float* loss_ptr = idx_out + N;

    char* ws = (char*)d_ws;
    size_t offA    = 0;
    size_t offB    = offA + (size_t)N * D_DIM * 2;
    size_t offS2   = offB + (size_t)K * D_DIM * 2;
    size_t offS1   = offS2 + (size_t)K * 4;
    size_t offCnt  = offS1 + (size_t)N * 4;
    size_t offCand = offCnt + (size_t)N * 4;
    size_t need    = offCand + (size_t)N * 32 * 4;

    const float loss_scale = 1.25f / ((float)N * (float)D_DIM);

    bool fast = (ws_size >= need) && (N % 256 == 0) && (K % 512 == 0);
    if (fast) {
        unsigned short* A = (unsigned short*)(ws + offA);
        unsigned short* B = (unsigned short*)(ws + offB);
        float* s2    = (float*)(ws + offS2);
        float* s1    = (float*)(ws + offS1);
        unsigned* cnt  = (unsigned*)(ws + offCnt);
        unsigned* cand = (unsigned*)(ws + offCand);

        k_norms<<<(K + 63) / 64, 64, 0, stream>>>(emb, s2, K, loss_ptr, nullptr);
        k_norms<<<(N + 63) / 64, 64, 0, stream>>>(x, s1, N, nullptr, cnt);
        k_cvt_bf16<<<(N * (D_DIM / 8)) / 256, 256, 0, stream>>>(x, A, (size_t)N * (D_DIM / 8));
        k_cvt_bf16<<<(K * (D_DIM / 8)) / 256, 256, 0, stream>>>(emb, B, (size_t)K * (D_DIM / 8));
        k_score<<<dim3(N / 128, 2), 512, 0, stream>>>(A, B, s2, cnt, cand, N, K);
        k_refine<<<N / 8, 256, 0, stream>>>(x, emb, s1, s2, cnt, cand, idx_out, N, K);
    } else {
        float* s2 = (float*)d_ws;
        float* s1 = s2 + K;
        k_norms<<<(K + 63) / 64, 64, 0, stream>>>(emb, s2, K, loss_ptr, nullptr);
        k_norms<<<(N + 63) / 64, 64, 0, stream>>>(x, s1, N, nullptr, nullptr);
        k_argmin<<<N / BM, 256, 0, stream>>>(x, emb, s1, s2, idx_out, N, K);
    }
    k_gather<<<(N + 15) / 16, 256, 0, stream>>>(x, emb, idx_out, out, loss_ptr, loss_scale, N);
}